// Round 1
// baseline (879.336 us; speedup 1.0000x reference)
//
#include <hip/hip_runtime.h>

// ---------------------------------------------------------------------------
// T5-style attention, B=4 S=2048 H=16 dk=64, D_MODEL=1024, buckets=32.
// Outputs: out [4,2048,1024] f32, then masks [4,16,2048,2048] f32.
// Scratch lives inside d_out's masks region (written last). d_ws unused.
// ---------------------------------------------------------------------------

typedef __attribute__((ext_vector_type(8))) short bf16x8;
typedef __attribute__((ext_vector_type(4))) float f32x4;
typedef __attribute__((ext_vector_type(8))) unsigned short u16x8;

#define MFMA16(a, b, c) __builtin_amdgcn_mfma_f32_16x16x32_bf16((a), (b), (c), 0, 0, 0)

#define ASYNC_COPY16(g, l)                                                              \
  __builtin_amdgcn_global_load_lds((const __attribute__((address_space(1))) void*)(g),  \
                                   (__attribute__((address_space(3))) void*)(l), 16, 0, 0)

__device__ __forceinline__ unsigned short f2bf(float f) {
  unsigned u = __float_as_uint(f);
  u += 0x7FFFu + ((u >> 16) & 1u);   // round-to-nearest-even
  return (unsigned short)(u >> 16);
}

// Exact integer-threshold version of the T5 bidirectional bucket (verified
// against fp32/fp64 reference evaluation; boundaries never straddled).
__device__ __forceinline__ int t5_bucket(int rel) {
  int bkt = (rel > 0) ? 16 : 0;
  int d = (rel < 0) ? -rel : rel;
  int v;
  if (d < 8) v = d;
  else if (d < 12) v = 8;
  else if (d < 16) v = 9;
  else if (d < 23) v = 10;
  else if (d < 32) v = 11;
  else if (d < 46) v = 12;
  else if (d < 64) v = 13;
  else if (d < 91) v = 14;
  else v = 15;
  return bkt + v;
}

// --------------------------- f32 -> bf16 cast ------------------------------
__global__ __launch_bounds__(256) void cast_kernel(const float* __restrict__ src,
                                                   unsigned short* __restrict__ dst, int n) {
  int i = (blockIdx.x * 256 + threadIdx.x) * 4;
  if (i >= n) return;
  float4 v = *(const float4*)(src + i);
  ushort4 o;
  o.x = f2bf(v.x); o.y = f2bf(v.y); o.z = f2bf(v.z); o.w = f2bf(v.w);
  *(ushort4*)(dst + i) = o;
}

// --------------------- bf16 GEMM: C = A * B^T (+bias) ----------------------
// A [M,K] row-major bf16, Bt [N,K] row-major bf16 (i.e. weights as given).
// 128x128 tile, BK=32, 4 waves (2x2), 16x16x32 MFMA, global_load_lds width 16,
// XOR-swizzled LDS (16B unit ^ (row>>1)&3) so ds_read_b128 is conflict-free.
template <bool OUT_BF16>
__global__ __launch_bounds__(256) void gemm_bt(const unsigned short* __restrict__ A,
                                               const unsigned short* __restrict__ Bt,
                                               const float* __restrict__ bias,
                                               void* __restrict__ Cout, int M, int N, int K) {
  __shared__ __align__(16) short As[128 * 32];
  __shared__ __align__(16) short Bs[128 * 32];
  const int lane = threadIdx.x & 63;
  const int wave = threadIdx.x >> 6;
  const int m0 = blockIdx.x * 128;
  const int n0 = blockIdx.y * 128;
  const int wr = wave >> 1, wc = wave & 1;

  f32x4 acc[4][4] = {};

  // staging geometry: chunk c covers LDS rows [c*16, c*16+16), 64B each.
  const int lrow = lane >> 2;                        // row within chunk
  const int lu = (lane & 3) ^ ((lane >> 3) & 3);     // swizzled logical 16B unit

  for (int k0 = 0; k0 < K; k0 += 32) {
#pragma unroll
    for (int q = 0; q < 2; ++q) {
      int c = wave * 2 + q;
      int row = c * 16 + lrow;
      ASYNC_COPY16(A + (size_t)(m0 + row) * K + k0 + lu * 8, As + c * 512);
      ASYNC_COPY16(Bt + (size_t)(n0 + row) * K + k0 + lu * 8, Bs + c * 512);
    }
    __syncthreads();

    bf16x8 af[4], bfr[4];
#pragma unroll
    for (int mi = 0; mi < 4; ++mi) {
      int row = wr * 64 + mi * 16 + (lane & 15);
      int u = (lane >> 4) ^ ((row >> 1) & 3);
      af[mi] = *(const bf16x8*)(As + row * 32 + u * 8);
    }
#pragma unroll
    for (int ni = 0; ni < 4; ++ni) {
      int row = wc * 64 + ni * 16 + (lane & 15);
      int u = (lane >> 4) ^ ((row >> 1) & 3);
      bfr[ni] = *(const bf16x8*)(Bs + row * 32 + u * 8);
    }
#pragma unroll
    for (int mi = 0; mi < 4; ++mi)
#pragma unroll
      for (int ni = 0; ni < 4; ++ni)
        acc[mi][ni] = MFMA16(af[mi], bfr[ni], acc[mi][ni]);
    __syncthreads();
  }

  float bvv[4];
#pragma unroll
  for (int ni = 0; ni < 4; ++ni) bvv[ni] = bias[n0 + wc * 64 + ni * 16 + (lane & 15)];

#pragma unroll
  for (int mi = 0; mi < 4; ++mi) {
    int rbase = m0 + wr * 64 + mi * 16 + ((lane >> 4) << 2);
#pragma unroll
    for (int ni = 0; ni < 4; ++ni) {
      int col = n0 + wc * 64 + ni * 16 + (lane & 15);
#pragma unroll
      for (int r = 0; r < 4; ++r) {
        float x = acc[mi][ni][r] + bvv[ni];
        if (OUT_BF16)
          ((unsigned short*)Cout)[(size_t)(rbase + r) * N + col] = f2bf(x);
        else
          ((float*)Cout)[(size_t)(rbase + r) * N + col] = x;
      }
    }
  }
}

// ------------------------- fused attention ---------------------------------
// Per block: (b,h) pair, 64 Q-rows. No-max online softmax (|logit| < ~0.02).
// LDS tiles padded to stride 72 elems (144B, odd multiple of 16B) -> no bank
// conflicts on ds_read_b128. P goes through per-wave LDS for the PV A-frag.
__global__ __launch_bounds__(256) void attn_fused(const unsigned short* __restrict__ Qg,
                                                  const unsigned short* __restrict__ Kg,
                                                  const unsigned short* __restrict__ Vg,
                                                  const float* __restrict__ am,
                                                  const float* __restrict__ rel_emb,
                                                  unsigned short* __restrict__ Og) {
  const int bh = blockIdx.y;
  const int b = bh >> 4, h = bh & 15;
  const int q0 = blockIdx.x << 6;
  const int tid = threadIdx.x;
  const int lane = tid & 63, wave = tid >> 6;

  __shared__ __align__(16) short Qs[64 * 72];
  __shared__ __align__(16) short Ks[64 * 72];
  __shared__ __align__(16) short Vt[64 * 72];   // transposed: Vt[d][j]
  __shared__ __align__(16) short Pl[4][16 * 72];
  __shared__ float remb[32];

  if (tid < 32) remb[tid] = rel_emb[tid * 16 + h];

  const size_t base = ((size_t)b * 2048) * 1024 + h * 64;

  {  // stage Q tile [64][64] -> Qs
    int row = tid >> 2, cu = (tid & 3) << 4;
    const unsigned short* src = Qg + base + (size_t)(q0 + row) * 1024 + cu;
    u16x8 v0 = *(const u16x8*)src;
    u16x8 v1 = *(const u16x8*)(src + 8);
    *(u16x8*)(Qs + row * 72 + cu) = v0;
    *(u16x8*)(Qs + row * 72 + cu + 8) = v1;
  }
  __syncthreads();

  bf16x8 qf[2];
  {
    int row = (wave << 4) + (lane & 15);
    const short* p = Qs + row * 72 + ((lane >> 4) << 3);
    qf[0] = *(const bf16x8*)p;
    qf[1] = *(const bf16x8*)(p + 32);
  }

  f32x4 acc[4] = {};
  float rsum[4] = {0.f, 0.f, 0.f, 0.f};
  const float inv = 1.0f / 4096.0f;
  const int ibase = q0 + (wave << 4) + ((lane >> 4) << 2);  // global i for r=0

  for (int kt = 0; kt < 32; ++kt) {
    const int j0 = kt << 6;
    __syncthreads();  // protect Ks/Vt from previous iteration's readers
    {
      int row = tid >> 2, cu = (tid & 3) << 4;
      const unsigned short* src = Kg + base + (size_t)(j0 + row) * 1024 + cu;
      u16x8 v0 = *(const u16x8*)src;
      u16x8 v1 = *(const u16x8*)(src + 8);
      *(u16x8*)(Ks + row * 72 + cu) = v0;
      *(u16x8*)(Ks + row * 72 + cu + 8) = v1;
      const unsigned short* vs = Vg + base + (size_t)(j0 + row) * 1024 + cu;
      u16x8 w0 = *(const u16x8*)vs;
      u16x8 w1 = *(const u16x8*)(vs + 8);
#pragma unroll
      for (int e = 0; e < 8; ++e) Vt[(cu + e) * 72 + row] = (short)w0[e];
#pragma unroll
      for (int e = 0; e < 8; ++e) Vt[(cu + 8 + e) * 72 + row] = (short)w1[e];
    }
    __syncthreads();

    // S = Q K^T  (C[i][j], i=rows of this wave, j tile-local)
    f32x4 sacc[4] = {};
#pragma unroll
    for (int kk = 0; kk < 2; ++kk) {
      const int koff = (kk << 5) + ((lane >> 4) << 3);
#pragma unroll
      for (int fj = 0; fj < 4; ++fj) {
        int row = (fj << 4) + (lane & 15);
        bf16x8 kf = *(const bf16x8*)(Ks + row * 72 + koff);
        sacc[fj] = MFMA16(qf[kk], kf, sacc[fj]);
      }
    }

    // P = exp((S + pos_bias + attn_mask)/4096); accumulate row sums; P -> LDS
#pragma unroll
    for (int fj = 0; fj < 4; ++fj) {
      int j = j0 + (fj << 4) + (lane & 15);
      const float* amp = am + ((size_t)b * 2048 + ibase) * 2048 + j;
#pragma unroll
      for (int r = 0; r < 4; ++r) {
        int rel = j - (ibase + r);
        float pb = remb[t5_bucket(rel)];
        float a = amp[(size_t)r * 2048];
        float p = __expf((sacc[fj][r] + pb + a) * inv);
        rsum[r] += p;
        Pl[wave][(((lane >> 4) << 2) + r) * 72 + (fj << 4) + (lane & 15)] = (short)f2bf(p);
      }
    }
    __syncthreads();  // Pl cross-lane visibility (and keeps waves in step)

    // O += P V   (A = P [i][j], B = V^T via Vt[d][j])
#pragma unroll
    for (int kk = 0; kk < 2; ++kk) {
      const int koff = (kk << 5) + ((lane >> 4) << 3);
      bf16x8 pf = *(const bf16x8*)(&Pl[wave][(lane & 15) * 72 + koff]);
#pragma unroll
      for (int fd = 0; fd < 4; ++fd) {
        int row = (fd << 4) + (lane & 15);
        bf16x8 vf = *(const bf16x8*)(Vt + row * 72 + koff);
        acc[fd] = MFMA16(pf, vf, acc[fd]);
      }
    }
  }

  // total row sums: reduce across the 16 j-lanes (xor 1,2,4,8)
#pragma unroll
  for (int m = 1; m < 16; m <<= 1)
#pragma unroll
    for (int r = 0; r < 4; ++r) rsum[r] += __shfl_xor(rsum[r], m, 64);

#pragma unroll
  for (int fd = 0; fd < 4; ++fd) {
    int d = (fd << 4) + (lane & 15);
#pragma unroll
    for (int r = 0; r < 4; ++r) {
      float o = acc[fd][r] / rsum[r];
      Og[base + (size_t)(ibase + r) * 1024 + d] = f2bf(o);
    }
  }
}

// ---------------------------- masks output ---------------------------------
// masks[b,h,i,j] = rel_emb[bucket(j-i)][h] + attention_masks[b,0,i,j]
// One block per (b,i): stage am row + bucket row in LDS, write 16 h-rows.
__global__ __launch_bounds__(256) void masks_kernel(const float* __restrict__ am,
                                                    const float* __restrict__ rel_emb,
                                                    float* __restrict__ mout) {
  const int bi = blockIdx.x;
  const int b = bi >> 11, i = bi & 2047;
  __shared__ float amrow[2048];
  __shared__ float remb[512];
  __shared__ unsigned char bkt[2048];
  for (int t = threadIdx.x; t < 512; t += 256) remb[t] = rel_emb[t];
  const float* arow = am + ((size_t)b * 2048 + i) * 2048;
  for (int t = threadIdx.x; t < 512; t += 256)
    *(float4*)(amrow + (t << 2)) = *(const float4*)(arow + (t << 2));
  for (int j = threadIdx.x; j < 2048; j += 256)
    bkt[j] = (unsigned char)t5_bucket(j - i);
  __syncthreads();
  for (int h = 0; h < 16; ++h) {
    float* dst = mout + (((size_t)(b * 16 + h)) * 2048 + i) * 2048;
    for (int t = threadIdx.x; t < 512; t += 256) {
      int j = t << 2;
      float4 o;
      o.x = remb[(bkt[j + 0] << 4) + h] + amrow[j + 0];
      o.y = remb[(bkt[j + 1] << 4) + h] + amrow[j + 1];
      o.z = remb[(bkt[j + 2] << 4) + h] + amrow[j + 2];
      o.w = remb[(bkt[j + 3] << 4) + h] + amrow[j + 3];
      *(float4*)(dst + j) = o;
    }
  }
}

// ---------------------------------------------------------------------------
extern "C" void kernel_launch(void* const* d_in, const int* in_sizes, int n_in,
                              void* d_out, int out_size, void* d_ws, size_t ws_size,
                              hipStream_t stream) {
  const float* hs  = (const float*)d_in[0];
  const float* am  = (const float*)d_in[1];
  const float* Wq  = (const float*)d_in[2];
  const float* bq  = (const float*)d_in[3];
  const float* Wk  = (const float*)d_in[4];
  const float* bk  = (const float*)d_in[5];
  const float* Wv  = (const float*)d_in[6];
  const float* bv  = (const float*)d_in[7];
  const float* Wo  = (const float*)d_in[8];
  const float* bo  = (const float*)d_in[9];
  const float* rel = (const float*)d_in[10];

  float* out = (float*)d_out;
  float* mout = out + (size_t)8388608;          // masks region
  char* SB = (char*)mout;                        // scratch inside masks region

  unsigned short* hsb = (unsigned short*)(SB);
  unsigned short* wqb = (unsigned short*)(SB + 16777216);
  unsigned short* wkb = (unsigned short*)(SB + 18874368);
  unsigned short* wvb = (unsigned short*)(SB + 20971520);
  unsigned short* wob = (unsigned short*)(SB + 23068672);
  unsigned short* qb  = (unsigned short*)(SB + 25165824);
  unsigned short* kb  = (unsigned short*)(SB + 41943040);
  unsigned short* vb  = (unsigned short*)(SB + 58720256);
  unsigned short* aob = (unsigned short*)(SB + 75497472);

  cast_kernel<<<8192, 256, 0, stream>>>(hs, hsb, 8388608);
  cast_kernel<<<1024, 256, 0, stream>>>(Wq, wqb, 1048576);
  cast_kernel<<<1024, 256, 0, stream>>>(Wk, wkb, 1048576);
  cast_kernel<<<1024, 256, 0, stream>>>(Wv, wvb, 1048576);
  cast_kernel<<<1024, 256, 0, stream>>>(Wo, wob, 1048576);

  gemm_bt<true><<<dim3(64, 8), 256, 0, stream>>>(hsb, wqb, bq, qb, 8192, 1024, 1024);
  gemm_bt<true><<<dim3(64, 8), 256, 0, stream>>>(hsb, wkb, bk, kb, 8192, 1024, 1024);
  gemm_bt<true><<<dim3(64, 8), 256, 0, stream>>>(hsb, wvb, bv, vb, 8192, 1024, 1024);

  attn_fused<<<dim3(32, 64), 256, 0, stream>>>(qb, kb, vb, am, rel, aob);

  gemm_bt<false><<<dim3(64, 8), 256, 0, stream>>>(aob, wob, bo, out, 8192, 1024, 1024);

  masks_kernel<<<8192, 256, 0, stream>>>(am, rel, mout);
}

// Round 2
// 549.260 us; speedup vs baseline: 1.6009x; 1.6009x over previous
//
#include <hip/hip_runtime.h>
#include <cmath>

// ---------------------------------------------------------------------------
// T5-style attention, B=4 S=2048 H=16 dk=64, D_MODEL=1024, buckets=32.
// Outputs: out [4,2048,1024] f32, then masks [4,16,2048,2048] f32.
// Scratch lives inside d_out's masks region (written last). d_ws unused.
// ---------------------------------------------------------------------------

typedef __attribute__((ext_vector_type(8))) short bf16x8;
typedef __attribute__((ext_vector_type(4))) float f32x4;
typedef __attribute__((ext_vector_type(8))) unsigned short u16x8;

#define MFMA16(a, b, c) __builtin_amdgcn_mfma_f32_16x16x32_bf16((a), (b), (c), 0, 0, 0)

#define ASYNC_COPY16(g, l)                                                              \
  __builtin_amdgcn_global_load_lds((const __attribute__((address_space(1))) void*)(g),  \
                                   (__attribute__((address_space(3))) void*)(l), 16, 0, 0)

__device__ __forceinline__ unsigned short f2bf(float f) {
  unsigned u = __float_as_uint(f);
  u += 0x7FFFu + ((u >> 16) & 1u);   // round-to-nearest-even
  return (unsigned short)(u >> 16);
}

// Exact integer-threshold version of the T5 bidirectional bucket (verified
// against fp32 reference evaluation; boundaries never straddled).
__device__ __forceinline__ int t5_bucket(int rel) {
  int bkt = (rel > 0) ? 16 : 0;
  int d = (rel < 0) ? -rel : rel;
  int v;
  if (d < 8) v = d;
  else if (d < 12) v = 8;
  else if (d < 16) v = 9;
  else if (d < 23) v = 10;
  else if (d < 32) v = 11;
  else if (d < 46) v = 12;
  else if (d < 64) v = 13;
  else if (d < 91) v = 14;
  else v = 15;
  return bkt + v;
}

// --------------------------- f32 -> bf16 cast ------------------------------
__global__ __launch_bounds__(256) void cast_kernel(const float* __restrict__ src,
                                                   unsigned short* __restrict__ dst, int n) {
  int i = (blockIdx.x * 256 + threadIdx.x) * 4;
  if (i >= n) return;
  float4 v = *(const float4*)(src + i);
  ushort4 o;
  o.x = f2bf(v.x); o.y = f2bf(v.y); o.z = f2bf(v.z); o.w = f2bf(v.w);
  *(ushort4*)(dst + i) = o;
}

// --------------------- bf16 GEMM: C = A * B^T (+bias) ----------------------
// A [M,K] row-major bf16, Bt [N,K] row-major bf16 (weights as given).
// 128x128 tile, BK=64 (m97 geometry), 4 waves (2x2), 16x16x32 MFMA,
// global_load_lds width 16 with pre-swizzled global source:
// LDS row = 64 elems = 8 x 16B units; unit pu holds global unit pu^(row&7).
// EPI: 0 = f32 out, 1 = bf16 out, 2 = bf16 transposed (V: [b,h,d,j] layout).
template <int EPI>
__global__ __launch_bounds__(256) void gemm_bt(const unsigned short* __restrict__ A,
                                               const unsigned short* __restrict__ Bt,
                                               const float* __restrict__ bias,
                                               void* __restrict__ Cout, int M, int N, int K) {
  __shared__ __align__(16) short As[128 * 64];
  __shared__ __align__(16) short Bs[128 * 64];
  const int lane = threadIdx.x & 63;
  const int wave = threadIdx.x >> 6;
  const int l15 = lane & 15, g = lane >> 4;
  const int m0 = blockIdx.x * 128;
  const int n0 = blockIdx.y * 128;
  const int wr = wave >> 1, wc = wave & 1;

  f32x4 acc[4][4] = {};

  const int srow_in = lane >> 3;   // row within 8-row staging chunk
  const int spu = lane & 7;        // physical 16B unit this lane fills

  for (int k0 = 0; k0 < K; k0 += 64) {
#pragma unroll
    for (int q = 0; q < 4; ++q) {
      const int rbase = (wave * 4 + q) * 8;
      const int row = rbase + srow_in;
      const int usrc = spu ^ (row & 7);            // pre-swizzled global unit
      ASYNC_COPY16(A + (size_t)(m0 + row) * K + k0 + usrc * 8, As + rbase * 64);
      ASYNC_COPY16(Bt + (size_t)(n0 + row) * K + k0 + usrc * 8, Bs + rbase * 64);
    }
    __syncthreads();

#pragma unroll
    for (int kk = 0; kk < 2; ++kk) {
      bf16x8 af[4], bfr[4];
#pragma unroll
      for (int mi = 0; mi < 4; ++mi) {
        int row = wr * 64 + mi * 16 + l15;
        int pu = (kk * 4 + g) ^ (row & 7);
        af[mi] = *(const bf16x8*)(As + row * 64 + pu * 8);
      }
#pragma unroll
      for (int ni = 0; ni < 4; ++ni) {
        int row = wc * 64 + ni * 16 + l15;
        int pu = (kk * 4 + g) ^ (row & 7);
        bfr[ni] = *(const bf16x8*)(Bs + row * 64 + pu * 8);
      }
#pragma unroll
      for (int mi = 0; mi < 4; ++mi)
#pragma unroll
        for (int ni = 0; ni < 4; ++ni)
          acc[mi][ni] = MFMA16(af[mi], bfr[ni], acc[mi][ni]);
    }
    __syncthreads();
  }

  float bvv[4];
#pragma unroll
  for (int ni = 0; ni < 4; ++ni) bvv[ni] = bias[n0 + wc * 64 + ni * 16 + l15];

#pragma unroll
  for (int mi = 0; mi < 4; ++mi) {
    int rbase = m0 + wr * 64 + mi * 16 + (g << 2);
#pragma unroll
    for (int ni = 0; ni < 4; ++ni) {
      int col = n0 + wc * 64 + ni * 16 + l15;
#pragma unroll
      for (int r = 0; r < 4; ++r) {
        float x = acc[mi][ni][r] + bvv[ni];
        if (EPI == 0) {
          ((float*)Cout)[(size_t)(rbase + r) * N + col] = x;
        } else if (EPI == 1) {
          ((unsigned short*)Cout)[(size_t)(rbase + r) * N + col] = f2bf(x);
        } else {
          // V transposed: m = b*2048 + j, col = h*64 + d -> [(b*1024+col)][j]
          int m = rbase + r;
          ((unsigned short*)Cout)[((size_t)((m >> 11) * 1024 + col) << 11) + (m & 2047)] =
              f2bf(x);
        }
      }
    }
  }
}

// ------------------------- fused attention ---------------------------------
// Per block: (b,h) pair, 64 Q-rows, 4 waves. No-max softmax (|logit| < ~0.02).
// Position bias pre-tabulated per block: pbc[rel+2047] = rel_emb[bucket][h]*SC
// with SC = log2(e)/4096, so p = exp2(fma(am,SC,fma(s,SC,pbc))).
// V arrives pre-transposed from the V-GEMM epilogue -> coalesced staging.
__global__ __launch_bounds__(256) void attn_fused(const unsigned short* __restrict__ Qg,
                                                  const unsigned short* __restrict__ Kg,
                                                  const unsigned short* __restrict__ Vtg,
                                                  const float* __restrict__ am,
                                                  const float* __restrict__ rel_emb,
                                                  unsigned short* __restrict__ Og) {
  const int bh = blockIdx.y;
  const int b = bh >> 4, h = bh & 15;
  const int q0 = blockIdx.x << 6;
  const int tid = threadIdx.x;
  const int lane = tid & 63, wave = tid >> 6;
  const int l15 = lane & 15, g = lane >> 4;

  __shared__ __align__(16) short Qs[64 * 72];
  __shared__ __align__(16) short Ks[64 * 72];
  __shared__ __align__(16) short Vt[64 * 72];   // Vt[d][j]
  __shared__ __align__(16) short Pl[4][16 * 72];
  __shared__ float pbc[4096];

  const float SC = 1.442695041f / 4096.0f;
  for (int t = tid; t < 4095; t += 256)
    pbc[t] = rel_emb[t5_bucket(t - 2047) * 16 + h] * SC;

  const size_t base = ((size_t)b * 2048) * 1024 + h * 64;     // Q/K/O token-major
  const size_t vtbase = (size_t)(b * 16 + h) << 17;           // Vt [b*16+h][64][2048]

  const int srow = tid >> 2, scu = (tid & 3) << 4;
  {  // stage Q tile [64][64]
    const unsigned short* src = Qg + base + (size_t)(q0 + srow) * 1024 + scu;
    u16x8 v0 = *(const u16x8*)src;
    u16x8 v1 = *(const u16x8*)(src + 8);
    *(u16x8*)(Qs + srow * 72 + scu) = v0;
    *(u16x8*)(Qs + srow * 72 + scu + 8) = v1;
  }
  __syncthreads();

  bf16x8 qf[2];
  {
    int row = (wave << 4) + l15;
    const short* p = Qs + row * 72 + (g << 3);
    qf[0] = *(const bf16x8*)p;
    qf[1] = *(const bf16x8*)(p + 32);
  }

  f32x4 acc[4] = {};
  float rsum[4] = {0.f, 0.f, 0.f, 0.f};
  const int ibase = q0 + (wave << 4) + (g << 2);  // global q-row for r=0

  const float* amr[4];
#pragma unroll
  for (int r = 0; r < 4; ++r)
    amr[r] = am + ((size_t)b * 2048 + ibase + r) * 2048 + l15;

  for (int kt = 0; kt < 32; ++kt) {
    const int j0 = kt << 6;
    __syncthreads();  // previous iteration's readers done with Ks/Vt
    {
      const unsigned short* ks = Kg + base + (size_t)(j0 + srow) * 1024 + scu;
      u16x8 v0 = *(const u16x8*)ks;
      u16x8 v1 = *(const u16x8*)(ks + 8);
      *(u16x8*)(Ks + srow * 72 + scu) = v0;
      *(u16x8*)(Ks + srow * 72 + scu + 8) = v1;
      const unsigned short* vs = Vtg + vtbase + ((size_t)srow << 11) + j0 + scu;
      u16x8 w0 = *(const u16x8*)vs;
      u16x8 w1 = *(const u16x8*)(vs + 8);
      *(u16x8*)(Vt + srow * 72 + scu) = w0;
      *(u16x8*)(Vt + srow * 72 + scu + 8) = w1;
    }
    __syncthreads();

    // S = Q K^T
    f32x4 sacc[4] = {};
#pragma unroll
    for (int kk = 0; kk < 2; ++kk) {
      const int koff = (kk << 5) + (g << 3);
#pragma unroll
      for (int fj = 0; fj < 4; ++fj) {
        bf16x8 kf = *(const bf16x8*)(Ks + ((fj << 4) + l15) * 72 + koff);
        sacc[fj] = MFMA16(qf[kk], kf, sacc[fj]);
      }
    }

    // P = exp2(SC*(s + am) + pbc[rel]); row sums; P -> per-wave LDS (bf16)
#pragma unroll
    for (int fj = 0; fj < 4; ++fj) {
      const int jl = (fj << 4) + l15;
      const int idx0 = j0 + jl - ibase + 2047;
#pragma unroll
      for (int r = 0; r < 4; ++r) {
        float a = amr[r][j0 + (fj << 4)];
        float x = fmaf(sacc[fj][r], SC, pbc[idx0 - r]);
        x = fmaf(a, SC, x);
        float p = exp2f(x);
        rsum[r] += p;
        Pl[wave][((g << 2) + r) * 72 + jl] = (short)f2bf(p);
      }
    }
    // Pl is wave-private: in-order LDS within a wave, no barrier needed.

    // O += P V  (A-frag = P rows, B-frag = Vt rows)
#pragma unroll
    for (int kk = 0; kk < 2; ++kk) {
      const int koff = (kk << 5) + (g << 3);
      bf16x8 pf = *(const bf16x8*)(&Pl[wave][l15 * 72 + koff]);
#pragma unroll
      for (int fd = 0; fd < 4; ++fd) {
        bf16x8 vf = *(const bf16x8*)(Vt + ((fd << 4) + l15) * 72 + koff);
        acc[fd] = MFMA16(pf, vf, acc[fd]);
      }
    }
  }

  // total row sums: reduce across the 16 j-lanes
#pragma unroll
  for (int m = 1; m < 16; m <<= 1)
#pragma unroll
    for (int r = 0; r < 4; ++r) rsum[r] += __shfl_xor(rsum[r], m, 64);

#pragma unroll
  for (int fd = 0; fd < 4; ++fd) {
    int d = (fd << 4) + l15;
#pragma unroll
    for (int r = 0; r < 4; ++r) {
      float o = acc[fd][r] / rsum[r];
      Og[base + (size_t)(ibase + r) * 1024 + d] = f2bf(o);
    }
  }
}

// ---------------------------- masks output ---------------------------------
__global__ __launch_bounds__(256) void masks_kernel(const float* __restrict__ am,
                                                    const float* __restrict__ rel_emb,
                                                    float* __restrict__ mout) {
  const int bi = blockIdx.x;
  const int b = bi >> 11, i = bi & 2047;
  __shared__ float amrow[2048];
  __shared__ float remb[512];
  __shared__ unsigned char bkt[2048];
  for (int t = threadIdx.x; t < 512; t += 256) remb[t] = rel_emb[t];
  const float* arow = am + ((size_t)b * 2048 + i) * 2048;
  for (int t = threadIdx.x; t < 512; t += 256)
    *(float4*)(amrow + (t << 2)) = *(const float4*)(arow + (t << 2));
  for (int j = threadIdx.x; j < 2048; j += 256)
    bkt[j] = (unsigned char)t5_bucket(j - i);
  __syncthreads();
  for (int h = 0; h < 16; ++h) {
    float* dst = mout + (((size_t)(b * 16 + h)) * 2048 + i) * 2048;
    for (int t = threadIdx.x; t < 512; t += 256) {
      int j = t << 2;
      float4 o;
      o.x = remb[(bkt[j + 0] << 4) + h] + amrow[j + 0];
      o.y = remb[(bkt[j + 1] << 4) + h] + amrow[j + 1];
      o.z = remb[(bkt[j + 2] << 4) + h] + amrow[j + 2];
      o.w = remb[(bkt[j + 3] << 4) + h] + amrow[j + 3];
      *(float4*)(dst + j) = o;
    }
  }
}

// ---------------------------------------------------------------------------
extern "C" void kernel_launch(void* const* d_in, const int* in_sizes, int n_in,
                              void* d_out, int out_size, void* d_ws, size_t ws_size,
                              hipStream_t stream) {
  const float* hs  = (const float*)d_in[0];
  const float* am  = (const float*)d_in[1];
  const float* Wq  = (const float*)d_in[2];
  const float* bq  = (const float*)d_in[3];
  const float* Wk  = (const float*)d_in[4];
  const float* bk  = (const float*)d_in[5];
  const float* Wv  = (const float*)d_in[6];
  const float* bv  = (const float*)d_in[7];
  const float* Wo  = (const float*)d_in[8];
  const float* bo  = (const float*)d_in[9];
  const float* rel = (const float*)d_in[10];

  float* out = (float*)d_out;
  float* mout = out + (size_t)8388608;          // masks region
  char* SB = (char*)mout;                        // scratch inside masks region

  unsigned short* hsb = (unsigned short*)(SB);
  unsigned short* wqb = (unsigned short*)(SB + 16777216);
  unsigned short* wkb = (unsigned short*)(SB + 18874368);
  unsigned short* wvb = (unsigned short*)(SB + 20971520);
  unsigned short* wob = (unsigned short*)(SB + 23068672);
  unsigned short* qb  = (unsigned short*)(SB + 25165824);
  unsigned short* kb  = (unsigned short*)(SB + 41943040);
  unsigned short* vtb = (unsigned short*)(SB + 58720256);
  unsigned short* aob = (unsigned short*)(SB + 75497472);

  cast_kernel<<<8192, 256, 0, stream>>>(hs, hsb, 8388608);
  cast_kernel<<<1024, 256, 0, stream>>>(Wq, wqb, 1048576);
  cast_kernel<<<1024, 256, 0, stream>>>(Wk, wkb, 1048576);
  cast_kernel<<<1024, 256, 0, stream>>>(Wv, wvb, 1048576);
  cast_kernel<<<1024, 256, 0, stream>>>(Wo, wob, 1048576);

  gemm_bt<1><<<dim3(64, 8), 256, 0, stream>>>(hsb, wqb, bq, qb, 8192, 1024, 1024);
  gemm_bt<1><<<dim3(64, 8), 256, 0, stream>>>(hsb, wkb, bk, kb, 8192, 1024, 1024);
  gemm_bt<2><<<dim3(64, 8), 256, 0, stream>>>(hsb, wvb, bv, vtb, 8192, 1024, 1024);

  attn_fused<<<dim3(32, 64), 256, 0, stream>>>(qb, kb, vtb, am, rel, aob);

  gemm_bt<0><<<dim3(64, 8), 256, 0, stream>>>(aob, wob, bo, out, 8192, 1024, 1024);

  masks_kernel<<<8192, 256, 0, stream>>>(am, rel, mout);
}